// Round 2
// 981.689 us; speedup vs baseline: 1.2034x; 1.2034x over previous
//
#include <hip/hip_runtime.h>
#include <math.h>
#include <stdint.h>

// CarryLSTMModel: B=8192, T=1024, D=16, H=16.
// Swapped-operand MFMA scan: z^T = W^T x state^T via mfma_f32_16x16x16_f16.
// Key identity (K=16 only): D-layout of h == B-operand layout of next step's
// MFMA -> the recurrence never leaves registers (no LDS, no shuffles).
// exp pre-scale (-log2e / -2log2e) folded into f16 weights; v_exp_f32 raw.

#define BB 8192
#define TT 1024
#define DD 16
#define HH 16

typedef __attribute__((ext_vector_type(4))) __fp16 half4;
typedef __attribute__((ext_vector_type(2))) __fp16 half2;
typedef __attribute__((ext_vector_type(4))) float f32x4;

#define L2E 1.4426950408889634f
#define CL1 17.312340490667555f  /* 12*log2(e): clamp for i,f,o gates */
#define CL2 34.624680981335110f  /* 24*log2(e): clamp for g gate and c */

__device__ __forceinline__ float ex2(float xx) {  // 2^x (v_exp_f32)
    float r; asm("v_exp_f32 %0, %1" : "=v"(r) : "v"(xx)); return r;
}

__global__ __launch_bounds__(64) void carry_lstm_mfma(
    const float* __restrict__ x,    // [B, T, 16]
    const float* __restrict__ Wi,   // [16, 64]
    const float* __restrict__ Wh,   // [16, 64]
    const float* __restrict__ b,    // [64]
    const float* __restrict__ Wd,   // [16, 2]
    const float* __restrict__ bd,   // [2]
    float* __restrict__ out)        // [B, 2]
{
    const int lane = threadIdx.x;
    const int lo4  = lane & 15;   // A-row u  |  B/D col m (element)
    const int s4   = lane >> 4;   // k-group (A,B)  |  row-group (C,D)
    const int e0   = blockIdx.x * 16;

    // ---- A operands (weights, transposed): A_g[u][k] at lane u+16*(k>>2),
    // reg k&3. Pre-scaled so z' = -log2e*z (i,f,o) / -2log2e*z (g):
    // sigmoid/tanh become pure 2^x rationals.
    half4 Ax[4], Ah[4];
    f32x4 bias[4];
#pragma unroll
    for (int g = 0; g < 4; ++g) {
        const float sc = (g == 2) ? (-2.f * L2E) : (-L2E);
#pragma unroll
        for (int e = 0; e < 4; ++e) {
            const int k = 4 * s4 + e;
            Ax[g][e] = (__fp16)(Wi[k * 64 + g * 16 + lo4] * sc);
            Ah[g][e] = (__fp16)(Wh[k * 64 + g * 16 + lo4] * sc);
        }
#pragma unroll
        for (int r = 0; r < 4; ++r)
            bias[g][r] = b[g * 16 + 4 * s4 + r] * sc;   // D row = 4*s4+r
    }

    // ---- x feed: lane (m,s4) loads x[e0+m][t][4*s4..4*s4+3], 16B coalesced
    // within each element row. 8-deep register prefetch queue.
    const float* xp = x + (size_t)(e0 + lo4) * (TT * DD) + s4 * 4;
    float4 xq[8];
#pragma unroll
    for (int j = 0; j < 8; ++j) xq[j] = *(const float4*)(xp + j * 16);

    // x-part + bias for t=0
    union H4 { half4 v; half2 h[2]; };
    H4 b0;
    b0.h[0] = __builtin_amdgcn_cvt_pkrtz(xq[0].x, xq[0].y);
    b0.h[1] = __builtin_amdgcn_cvt_pkrtz(xq[0].z, xq[0].w);
    f32x4 ax0 = __builtin_amdgcn_mfma_f32_16x16x16f16(Ax[0], b0.v, bias[0], 0, 0, 0);
    f32x4 ax1 = __builtin_amdgcn_mfma_f32_16x16x16f16(Ax[1], b0.v, bias[1], 0, 0, 0);
    f32x4 ax2 = __builtin_amdgcn_mfma_f32_16x16x16f16(Ax[2], b0.v, bias[2], 0, 0, 0);
    f32x4 ax3 = __builtin_amdgcn_mfma_f32_16x16x16f16(Ax[3], b0.v, bias[3], 0, 0, 0);

    half4 Bh = {};                       // h_0 = 0, already in B-layout
    float cr[4] = {0.f, 0.f, 0.f, 0.f};  // c for (m=lo4, u=4*s4+r), fp32
    const float* xpp = xp + 8 * 16;

    for (int tb = 0; tb < TT; tb += 8) {
        // final group: re-load own first rows (valid addr, results unused)
        const float* lp = (tb + 16 <= TT) ? xpp : xp;
#pragma unroll
        for (int j = 0; j < 8; ++j) {
            // ---- recurrence MFMAs (critical path: only need Bh)
            f32x4 aI = __builtin_amdgcn_mfma_f32_16x16x16f16(Ah[0], Bh, ax0, 0, 0, 0);
            f32x4 aF = __builtin_amdgcn_mfma_f32_16x16x16f16(Ah[1], Bh, ax1, 0, 0, 0);
            f32x4 aG = __builtin_amdgcn_mfma_f32_16x16x16f16(Ah[2], Bh, ax2, 0, 0, 0);
            f32x4 aO = __builtin_amdgcn_mfma_f32_16x16x16f16(Ah[3], Bh, ax3, 0, 0, 0);

            // ---- off-path: prefetch x_{t+8}; start x-part for t+1
            xq[j] = *(const float4*)(lp + j * 16);
            const float4 xn = xq[(j + 1) & 7];
            H4 bx;
            bx.h[0] = __builtin_amdgcn_cvt_pkrtz(xn.x, xn.y);
            bx.h[1] = __builtin_amdgcn_cvt_pkrtz(xn.z, xn.w);
            ax0 = __builtin_amdgcn_mfma_f32_16x16x16f16(Ax[0], bx.v, bias[0], 0, 0, 0);
            ax1 = __builtin_amdgcn_mfma_f32_16x16x16f16(Ax[1], bx.v, bias[1], 0, 0, 0);
            ax2 = __builtin_amdgcn_mfma_f32_16x16x16f16(Ax[2], bx.v, bias[2], 0, 0, 0);
            ax3 = __builtin_amdgcn_mfma_f32_16x16x16f16(Ax[3], bx.v, bias[3], 0, 0, 0);

            // ---- 4 cell updates; all in-lane (z' = -log2e*z scaled)
            float hh[4];
#pragma unroll
            for (int r = 0; r < 4; ++r) {
                const float ea = ex2(fminf(aI[r], CL1));   // e^{-zi}
                const float ef = ex2(fminf(aF[r], CL1));   // e^{-zf}
                const float G  = ex2(fminf(aG[r], CL2));   // e^{-2zg}
                const float eo = ex2(fminf(aO[r], CL1));   // e^{-zo}
                // c' = [c(1+ea)(1+G) + (1-G)(1+ef)] / [(1+ea)(1+ef)(1+G)]
                float u = fmaf(cr[r], ea, cr[r]);
                u = fmaf(u, G, u);
                const float s  = 1.f - G;
                const float s2 = fmaf(s, ef, s);
                const float num = u + s2;
                const float den = (ea + 1.f) * (ef + 1.f);
                const float den3 = fmaf(den, G, den);
                const float cn = num * __builtin_amdgcn_rcpf(den3);
                cr[r] = cn;
                // h = (1-C2) / [(1+C2)(1+eo)],  C2 = 2^{-2*log2e*c'}
                const float C2 = ex2(fminf(cn * (-2.f * L2E), CL2));
                const float hd = (1.f + C2) * (1.f + eo);
                hh[r] = (1.f - C2) * __builtin_amdgcn_rcpf(hd);
            }
            // D-layout == next B-layout: 2 packs and we're back in the loop
            H4 hu;
            hu.h[0] = __builtin_amdgcn_cvt_pkrtz(hh[0], hh[1]);
            hu.h[1] = __builtin_amdgcn_cvt_pkrtz(hh[2], hh[3]);
            Bh = hu.v;
        }
        xpp += 8 * 16;
    }

    // ---- head: logits = c_T @ Wd + bd (cell state), softmax over 2.
    // Lane holds c[m][4*s4+r]; reduce over s4 groups via xor-shuffles.
    float p0 = 0.f, p1 = 0.f;
#pragma unroll
    for (int r = 0; r < 4; ++r) {
        p0 += cr[r] * Wd[(4 * s4 + r) * 2 + 0];
        p1 += cr[r] * Wd[(4 * s4 + r) * 2 + 1];
    }
    p0 += __shfl_xor(p0, 16); p1 += __shfl_xor(p1, 16);
    p0 += __shfl_xor(p0, 32); p1 += __shfl_xor(p1, 32);
    if (lane < 16) {
        const float l0 = p0 + bd[0], l1 = p1 + bd[1];
        const float mx = fmaxf(l0, l1);
        const float E0 = __expf(l0 - mx), E1 = __expf(l1 - mx);
        const float inv = __builtin_amdgcn_rcpf(E0 + E1);
        float2 o; o.x = E0 * inv; o.y = E1 * inv;
        *(float2*)&out[(size_t)(e0 + lo4) * 2] = o;   // 16 lanes, 128B contiguous
    }
}

extern "C" void kernel_launch(void* const* d_in, const int* in_sizes, int n_in,
                              void* d_out, int out_size, void* d_ws, size_t ws_size,
                              hipStream_t stream) {
    const float* x  = (const float*)d_in[0];
    const float* Wi = (const float*)d_in[1];
    const float* Wh = (const float*)d_in[2];
    const float* b  = (const float*)d_in[3];
    const float* Wd = (const float*)d_in[4];
    const float* bd = (const float*)d_in[5];
    float* out = (float*)d_out;

    // 8192 elements / 16 per wave = 512 single-wave blocks
    hipLaunchKernelGGL(carry_lstm_mfma, dim3(BB / 16), dim3(64), 0, stream,
                       x, Wi, Wh, b, Wd, bd, out);
}